// Round 1
// baseline (54.239 us; speedup 1.0000x reference)
//
#include <hip/hip_runtime.h>
#include <hip/hip_fp16.h>

typedef _Float16 half8 __attribute__((ext_vector_type(8)));
typedef _Float16 half4 __attribute__((ext_vector_type(4)));
typedef float floatx4 __attribute__((ext_vector_type(4)));

#define KH 256      // H (inner dim)
#define NN 1024     // N = F*G*2 heads
#define BM 64       // rows per block
#define BN 64       // cols per n-tile
#define LDW 264     // f16 elems per LDS row (256 + 8 pad -> bank-conflict-free)
#define NT (NN / BN)

__global__ __launch_bounds__(256, 2)
void lfh_kernel(const float* __restrict__ x, const float* __restrict__ W,
                const float* __restrict__ bias, float* __restrict__ out) {
    __shared__ _Float16 Ws[2][BN * LDW];   // 2 x 33 KB, double-buffered W tile

    const int t   = threadIdx.x;
    const int w   = t >> 6;       // wave 0..3 -> rows w*16..w*16+15
    const int l   = t & 63;
    const int l15 = l & 15;
    const int lq  = l >> 4;       // 0..3
    const int m0  = blockIdx.x * BM;

    // ---- A fragments: fp32 -> f16, kept entirely in registers ----
    // 16x16x32 f16 A layout: lane l holds A[row = l&15][k = (l>>4)*8 + j], j=0..7
    half8 afrag[8];
    {
        const int arow = m0 + w * 16 + l15;
        const float* xr = x + (size_t)arow * KH;
        #pragma unroll
        for (int ks = 0; ks < 8; ++ks) {
            const int kb = ks * 32 + lq * 8;
            floatx4 lo = *(const floatx4*)(xr + kb);
            floatx4 hi = *(const floatx4*)(xr + kb + 4);
            half8 f;
            f[0] = (_Float16)lo[0]; f[1] = (_Float16)lo[1];
            f[2] = (_Float16)lo[2]; f[3] = (_Float16)lo[3];
            f[4] = (_Float16)hi[0]; f[5] = (_Float16)hi[1];
            f[6] = (_Float16)hi[2]; f[7] = (_Float16)hi[3];
            afrag[ks] = f;
        }
    }

    // ---- stage W tile 0 (fp32 -> f16 -> LDS), fully coalesced 4KB/instr ----
    #pragma unroll
    for (int j = 0; j < 16; ++j) {
        const int flat = j * 1024 + t * 4;     // covers 64x256 floats exactly once
        const int nl = flat >> 8, k = flat & 255;
        floatx4 v = *(const floatx4*)(W + (size_t)nl * KH + k);
        half4 h;
        h[0] = (_Float16)v[0]; h[1] = (_Float16)v[1];
        h[2] = (_Float16)v[2]; h[3] = (_Float16)v[3];
        *(half4*)&Ws[0][nl * LDW + k] = h;
    }
    __syncthreads();

    int cur = 0;
    for (int nt = 0; nt < NT; ++nt) {
        const int n0 = nt * BN;

        // issue next W tile's global loads early (hide L2 latency under MFMA)
        floatx4 wreg[16];
        if (nt + 1 < NT) {
            const float* Wn = W + (size_t)(n0 + BN) * KH;
            #pragma unroll
            for (int j = 0; j < 16; ++j) {
                const int flat = j * 1024 + t * 4;
                wreg[j] = *(const floatx4*)(Wn + ((flat >> 8) * KH + (flat & 255)));
            }
        }

        floatx4 acc[4];
        #pragma unroll
        for (int nf = 0; nf < 4; ++nf) acc[nf] = (floatx4)0.0f;

        #pragma unroll
        for (int ks = 0; ks < 8; ++ks) {
            #pragma unroll
            for (int nf = 0; nf < 4; ++nf) {
                // B (=W^T) fragment: lane l holds W[n = nf*16 + l&15][k = (l>>4)*8 + j]
                half8 wf = *(const half8*)&Ws[cur][(nf * 16 + l15) * LDW + ks * 32 + lq * 8];
                acc[nf] = __builtin_amdgcn_mfma_f32_16x16x32_f16(afrag[ks], wf, acc[nf], 0, 0, 0);
            }
        }

        // convert + write next tile into the other LDS buffer
        if (nt + 1 < NT) {
            #pragma unroll
            for (int j = 0; j < 16; ++j) {
                const int flat = j * 1024 + t * 4;
                const int nl = flat >> 8, k = flat & 255;
                half4 h;
                h[0] = (_Float16)wreg[j][0]; h[1] = (_Float16)wreg[j][1];
                h[2] = (_Float16)wreg[j][2]; h[3] = (_Float16)wreg[j][3];
                *(half4*)&Ws[cur ^ 1][nl * LDW + k] = h;
            }
        }
        __syncthreads();  // one barrier per n-tile: writes(cur^1) visible before next reads

        // ---- epilogue: bias + sigmoid + fp32 store ----
        // C/D layout: col = lane&15, row = (lane>>4)*4 + j  [verified m89/m91]
        #pragma unroll
        for (int nf = 0; nf < 4; ++nf) {
            const int col = n0 + nf * 16 + l15;
            const float bv = bias[col];
            #pragma unroll
            for (int j = 0; j < 4; ++j) {
                const int row = m0 + w * 16 + lq * 4 + j;
                const float z = acc[nf][j] + bv;
                out[(size_t)row * NN + col] = 1.0f / (1.0f + __expf(-z));
            }
        }
        cur ^= 1;
    }
}

extern "C" void kernel_launch(void* const* d_in, const int* in_sizes, int n_in,
                              void* d_out, int out_size, void* d_ws, size_t ws_size,
                              hipStream_t stream) {
    const float* x = (const float*)d_in[0];
    const float* W = (const float*)d_in[1];
    const float* b = (const float*)d_in[2];
    float* out = (float*)d_out;
    const int Btot = in_sizes[0] / KH;      // 32768
    dim3 grid(Btot / BM), block(256);
    lfh_kernel<<<grid, block, 0, stream>>>(x, W, b, out);
}

// Round 2
// 51.749 us; speedup vs baseline: 1.0481x; 1.0481x over previous
//
#include <hip/hip_runtime.h>
#include <hip/hip_fp16.h>

typedef _Float16 half8 __attribute__((ext_vector_type(8)));
typedef float floatx4 __attribute__((ext_vector_type(4)));

#define KH 256            // H (inner / K dim)
#define NN 1024           // N heads
#define BM 64             // b-rows per block (4 waves x 16)
#define STN 64            // n-cols per supertile
#define NST (NN / STN)    // 16 supertiles
#define ST_F16 (STN * KH) // 16384 f16 per supertile (32 KB)

// ---------------- pack kernel: W fp32 -> f16, MFMA-fragment order ----------
// packed f16 index: ((g*8 + ks)*64 + lane)*8 + j
//   where n = g*16 + (lane&15), k = ks*32 + (lane>>4)*8 + j
__global__ __launch_bounds__(256)
void pack_w(const float* __restrict__ W, _Float16* __restrict__ P) {
    const int u  = blockIdx.x * 256 + threadIdx.x;   // 32768 threads total
    const int g  = u >> 9;
    const int ks = (u >> 6) & 7;
    const int l  = u & 63;
    const int n  = g * 16 + (l & 15);
    const int kb = ks * 32 + ((l >> 4) << 3);
    const float* src = W + (size_t)n * KH + kb;
    floatx4 lo = *(const floatx4*)src;
    floatx4 hi = *(const floatx4*)(src + 4);
    half8 h;
    h[0] = (_Float16)lo[0]; h[1] = (_Float16)lo[1];
    h[2] = (_Float16)lo[2]; h[3] = (_Float16)lo[3];
    h[4] = (_Float16)hi[0]; h[5] = (_Float16)hi[1];
    h[6] = (_Float16)hi[2]; h[7] = (_Float16)hi[3];
    *(half8*)(P + (size_t)u * 8) = h;                // fully coalesced 16B/lane
}

// ---------------- main kernel ----------------------------------------------
__global__ __launch_bounds__(256, 2)
void lfh_main(const float* __restrict__ x, const _Float16* __restrict__ P,
              const float* __restrict__ bias, float* __restrict__ out) {
    __shared__ _Float16 Ws[2][ST_F16];   // 2 x 32 KB double buffer

    const int t   = threadIdx.x;
    const int w   = t >> 6;
    const int l   = t & 63;
    const int l15 = l & 15;
    const int lq  = l >> 4;
    const int m0  = blockIdx.x * BM;
    const int brow = m0 + w * 16 + l15;

    // ---- A fragments (x rows), fp32 -> f16, kept in registers -------------
    half8 afrag[8];
    {
        const float* xr = x + (size_t)brow * KH;
        #pragma unroll
        for (int ks = 0; ks < 8; ++ks) {
            const int kb = ks * 32 + lq * 8;
            floatx4 lo = *(const floatx4*)(xr + kb);
            floatx4 hi = *(const floatx4*)(xr + kb + 4);
            half8 f;
            f[0] = (_Float16)lo[0]; f[1] = (_Float16)lo[1];
            f[2] = (_Float16)lo[2]; f[3] = (_Float16)lo[3];
            f[4] = (_Float16)hi[0]; f[5] = (_Float16)hi[1];
            f[6] = (_Float16)hi[2]; f[7] = (_Float16)hi[3];
            afrag[ks] = f;
        }
    }

    // ---- async stage of one 32KB supertile: 8 x (256 threads x 16B) -------
    auto stage = [&](int st, _Float16* dst) {
        const _Float16* gsrc = P + (size_t)st * ST_F16;
        #pragma unroll
        for (int r = 0; r < 8; ++r) {
            __builtin_amdgcn_global_load_lds(
                (const __attribute__((address_space(1))) void*)(gsrc + r * 2048 + t * 8),
                (__attribute__((address_space(3))) void*)(dst + r * 2048 + t * 8),
                16, 0, 0);
        }
    };

    stage(0, Ws[0]);
    __syncthreads();

    int cur = 0;
    for (int st = 0; st < NST; ++st) {
        if (st + 1 < NST) stage(st + 1, Ws[cur ^ 1]);   // prefetch next tile

        const _Float16* Bt = Ws[cur];
        #pragma unroll
        for (int nf = 0; nf < 4; ++nf) {
            floatx4 acc = (floatx4)0.0f;
            #pragma unroll
            for (int ks = 0; ks < 8; ++ks) {
                // linear, conflict-free: each lane reads its own 16B slot
                half8 wf = *(const half8*)(Bt + ((nf * 8 + ks) * 64 + l) * 8);
                // swapped operands: M-dim = n (W rows), N-dim = b (x rows)
                acc = __builtin_amdgcn_mfma_f32_16x16x32_f16(wf, afrag[ks], acc, 0, 0, 0);
            }
            // D layout: col = b (lane&15), row = n_local = lq*4 + j
            const int nb = st * STN + nf * 16 + lq * 4;
            floatx4 bv = *(const floatx4*)(bias + nb);
            floatx4 r;
            #pragma unroll
            for (int j = 0; j < 4; ++j) {
                const float z = acc[j] + bv[j];
                r[j] = __builtin_amdgcn_rcpf(1.0f + __expf(-z));
            }
            __builtin_nontemporal_store(r, (floatx4*)(out + (size_t)brow * NN + nb));
        }
        __syncthreads();   // drains prefetch into cur^1; next iter reads it
        cur ^= 1;
    }
}

extern "C" void kernel_launch(void* const* d_in, const int* in_sizes, int n_in,
                              void* d_out, int out_size, void* d_ws, size_t ws_size,
                              hipStream_t stream) {
    const float* x = (const float*)d_in[0];
    const float* W = (const float*)d_in[1];
    const float* b = (const float*)d_in[2];
    float* out = (float*)d_out;
    _Float16* P = (_Float16*)d_ws;            // 512 KB packed f16 W

    pack_w<<<dim3(128), dim3(256), 0, stream>>>(W, P);

    const int Btot = in_sizes[0] / KH;        // 32768
    lfh_main<<<dim3(Btot / BM), dim3(256), 0, stream>>>(x, P, b, out);
}